// Round 1
// 157.596 us; speedup vs baseline: 1.0362x; 1.0362x over previous
//
#include <hip/hip_runtime.h>
#include <hip/hip_fp16.h>
#include <stdint.h>

#define NQ     14
#define NL     4
#define BATCH  2048
#define DIM    16384

using half8  = __attribute__((ext_vector_type(8)))  _Float16;
using half4  = __attribute__((ext_vector_type(4)))  _Float16;
using f32x16 = __attribute__((ext_vector_type(16))) float;
using f32x4  = __attribute__((ext_vector_type(4)))  float;

// ================= compile-time maps =================
// CNOT ring (ctrl q -> tgt q+1 mod 14, q=0..13 sequentially; amp-bit p = 13-qubit):
//   out bit p (p<=12) = XOR(in bits p..13) ; out bit 13 = XOR(in bits 0..12)
// => image mask of INPUT bit b:  M(e_b) = bits0..b | bit13 (b<=12) ; M(e_13) = bits0..12
// (consistency check: M(e_2) = 0x2007 == old kernel's Me[0])
constexpr uint32_t mmask(int b) { return b < 13 ? (((1u << (b + 1)) - 1u) | 0x2000u) : 0x1FFFu; }
// L_A byte address of amp a (4 B/amp: packed (x,y) f16):
//   col = a>>5 (128 B/col), 16B-granule = (a>>2)&7 XOR-swizzled by col&7, inner = a&3.
// All fields are disjoint bit-selects combined with XOR => XOR-linear over bits of a,
// so evaluating at a multi-bit mask gives the XOR of single-bit images.
constexpr uint32_t laddr(uint32_t a) {
  return ((a >> 5) << 7) ^ (((((a >> 2) & 7u) ^ ((a >> 5) & 7u)) & 7u) << 4) ^ ((a & 3u) << 2);
}
constexpr uint32_t IMG(int b) { return laddr(mmask(b)); }  // addr-image of amp-bit b after CNOT

struct TabEmb { uint32_t v[32]; constexpr TabEmb() : v() {
  for (int k = 0; k < 32; ++k) { uint32_t x = 0;
    for (int b = 0; b < 5; ++b) if ((k >> b) & 1) x ^= IMG(b); v[k] = x; } } };
constexpr TabEmb EMBT{};

// GC scatter element constants: element bits (i -> a4..a6, reg -> a0..a1)
struct TabSc { uint32_t v[8][4]; constexpr TabSc() : v() {
  for (int i = 0; i < 8; ++i) for (int r = 0; r < 4; ++r) { uint32_t x = 0;
    if (r & 1) x ^= IMG(0); if (r & 2) x ^= IMG(1);
    if (i & 1) x ^= IMG(4); if (i & 2) x ^= IMG(5); if (i & 4) x ^= IMG(6);
    v[i][r] = x; } } };
constexpr TabSc SCT{};

// GB -> L_C element constants. L_C: 64 B/col'', addr = col''*64
//   ^ (((k''>>2) ^ sg(col''))<<4) ^ (((k''&3) ^ sin(col''))<<2)
//   sg(c) = ((c ^ (c>>2))&3) ^ ((c>>7)&3) ; sin(c) = (c>>5)&3
// element part: ce = (e&3)|((e>>2)<<3)  (c'_M without the hi-lane bit)
struct TabEc { uint32_t v[16]; constexpr TabEc() : v() {
  for (int e = 0; e < 16; ++e) { uint32_t ce = (uint32_t)((e & 3) | ((e >> 2) << 3));
    v[e] = (ce << 6) ^ (((ce ^ (ce >> 2)) & 3u) << 4); } } };
constexpr TabEc ECT{};

__device__ __forceinline__ half8 h8(uint32_t a, uint32_t b, uint32_t c, uint32_t d) {
  union { uint32_t u[4]; half8 h; } z; z.u[0]=a; z.u[1]=b; z.u[2]=c; z.u[3]=d; return z.h; }
__device__ __forceinline__ half4 h4v(uint32_t a, uint32_t b) {
  union { uint32_t u[2]; half4 h; } z; z.u[0]=a; z.u[1]=b; return z.h; }
__device__ __forceinline__ uint4 ld16(const char* p) {
  return *(const uint4*)__builtin_assume_aligned(p, 16); }
__device__ __forceinline__ void st16(char* p, uint4 v) {
  *(uint4*)__builtin_assume_aligned(p, 16) = v; }
__device__ __forceinline__ uint32_t pkh2(float a, float b) {
  return __builtin_bit_cast(uint32_t, __floats2half2_rn(a, b)); }

// ================= prep kernel: build U matrices (R, I) per layer/group into d_ws =================
// Per layer (halfs): GA_R[32][32] @0, GA_I @1024, GB_R @2048, GB_I @3072, GC_R[16][16] @4096, GC_I @4352
// layer stride 4608 halfs; layers li=0..2 use circuit layers 1..3 (layer 0 is folded into embedding).
// Blob stores U[r][k] (RX tensor is symmetric), read as the mfma B-operand U^T fragments.
__global__ void uprep_kernel(const float* __restrict__ params, __half* __restrict__ U) {
  const int id = blockIdx.x * 256 + threadIdx.x;   // 27*256 = 6912 cells exactly
  int li, grp, r, k, nb, off, mstride;
  if (id < 6144) { li = id >> 11; const int sub = id & 2047;
    grp = sub >> 10; const int cell = sub & 1023; r = cell >> 5; k = cell & 31; nb = 5;
    off = li * 4608 + grp * 2048 + r * 32 + k; mstride = 1024; }
  else { const int id2 = id - 6144; li = id2 >> 8; const int cell = id2 & 255;
    grp = 2; r = cell >> 4; k = cell & 15; nb = 4;
    off = li * 4608 + 4096 + r * 16 + k; mstride = 256; }
  const float* th = params + (li + 1) * NQ;
  float mag = 1.f; int d = 0;
  for (int j = 0; j < nb; ++j) {
    const int pbit = (grp == 0) ? j : (grp == 1) ? 5 + j : 10 + j;  // amp bit
    const float ph = 0.5f * th[13 - pbit];                          // qubit = 13 - ampbit
    const int df = ((r >> j) ^ (k >> j)) & 1;
    mag *= df ? sinf(ph) : cosf(ph);
    d += df;
  }
  // entry = (-i)^d * mag
  float R = 0.f, I = 0.f;
  switch (d & 3) { case 0: R = mag; break; case 1: I = -mag; break;
                   case 2: R = -mag; break; default: I = mag; break; }
  U[off] = __float2half_rn(R);
  U[off + mstride] = __float2half_rn(I);
}

// ================= main kernel =================
// State: 16384 amps, 4 B each ((x,y) f16), in one 64 KB LDS buffer, re-laid-out in place:
//  L_A: col = a bits5..13, k = a bits0..4   (GA rotates qubits 13..9)
//  L_B: col = a bits11..13|bit10|bits0..4,  k = a bits5..9  (GB rotates qubits 8..4)
//  L_C: col'' = a bits0..9, k'' = a bits10..13 (GC rotates qubits 3..0)
// Each group = D[c,r] = sum_k S[c,k]*U[r,k] via mfma (state = A operand, U^T = B operand).
// CNOT ring folded into XOR-linear scatter addresses (embed & GC writes); final CNOT folded
// into the measurement Walsh masks. All LDS patterns granule-XOR swizzled (bank-checked).
__global__ __launch_bounds__(512)
__attribute__((amdgpu_waves_per_eu(4, 4)))
void qsim_kernel(const float* __restrict__ x, const float* __restrict__ params,
                 const __half* __restrict__ U, float* __restrict__ out) {
  __shared__ uint32_t lds[DIM];          // 64 KB state
  __shared__ float red[8][16];
  __shared__ float exc[NQ], exs[NQ];
  char* const sb = (char*)lds;

  const int b = blockIdx.x;
  const int t = threadIdx.x;
  const int w = t >> 6, l = t & 63;
  const int hi = l >> 5, l31 = l & 31, l15 = l & 15, h4 = (l >> 4) & 3;
  const int swz = l & 7;

  // layer-0 RX folded into embedding: RX(theta)RX(x)|0> = RX(x+theta)|0>
  if (t < NQ) { const float xv = x[b * NQ + t] + params[t];
                exc[t] = cosf(0.5f * xv); exs[t] = sinf(0.5f * xv); }
  __syncthreads();

  // ---- per-lane bases ----
  const uint32_t colAB = (uint32_t)(((w << 6) | l31) << 7);   // wave window (8 KB), +n<<12 per tile
  const uint32_t sgl = (uint32_t)(((l15 ^ (l15 >> 2)) ^ w) & 3);
  const uint32_t gcr = (uint32_t)((w << 13) | (l15 << 6) | (((h4 ^ (int)sgl) & 3) << 4));
  const uint32_t lbc = ((uint32_t)l31 << 11) ^ ((uint32_t)hi << 8)
      ^ ((uint32_t)(((w >> 1) ^ ((l31 >> 2) & 3) ^ hi) & 3) << 4)
      ^ ((uint32_t)(((w << 1) ^ l) & 3) << 2);
  uint32_t scb = 0;
  { if (l & 16) scb ^= IMG(2);
    if (l & 32) scb ^= IMG(3);
#pragma unroll
    for (int j = 0; j < 4; ++j) if ((l15 >> j) & 1) scb ^= IMG(10 + j);
#pragma unroll
    for (int j = 0; j < 3; ++j) if ((w >> j) & 1) scb ^= IMG(7 + j); }

  // ---- embedding: thread t computes amps a = 32t+k, writes value to laddr(M(a)) (layer-0 CNOT) ----
  {
    float pb = 1.f;
#pragma unroll
    for (int j = 0; j < 9; ++j) pb *= ((t >> j) & 1) ? exs[8 - j] : exc[8 - j];  // a bit 5+j -> qubit 8-j
    uint32_t eb = 0;
#pragma unroll
    for (int j = 0; j < 9; ++j) if ((t >> j) & 1) eb ^= IMG(5 + j);
    float fm[8], fl[4];
#pragma unroll
    for (int m = 0; m < 8; ++m)
      fm[m] = ((m & 1) ? exs[11] : exc[11]) * ((m & 2) ? exs[10] : exc[10]) * ((m & 4) ? exs[9] : exc[9]);
#pragma unroll
    for (int m = 0; m < 4; ++m)
      fl[m] = ((m & 1) ? exs[13] : exc[13]) * ((m & 2) ? exs[12] : exc[12]);
    const int pct = __popc(t);
#pragma unroll
    for (int k = 0; k < 32; ++k) {
      const float f = pb * fm[k >> 2] * fl[k & 3];
      const int pc = (pct + __popc(k)) & 3;                  // (-i)^pc phase
      const float xr = (pc == 0) ? f : ((pc == 2) ? -f : 0.f);
      const float yi = (pc == 1) ? -f : ((pc == 3) ? f : 0.f);
      *(uint32_t*)(sb + (eb ^ EMBT.v[k])) = pkh2(xr, yi);
    }
  }
  __syncthreads();

#pragma unroll 1
  for (int li = 0; li < 3; ++li) {
    const __half* Ul = U + li * 4608;

    // ============ GA: qubits 13..9 (amp bits 0..4); wave-private in-place ============
    {
      half8 bR[2], bI[2];
#pragma unroll
      for (int s = 0; s < 2; ++s) {
        const __half* up = Ul + l31 * 32 + s * 16 + hi * 8;   // blob [r=l31][k=16s+8hi]
        bR[s] = *(const half8*)__builtin_assume_aligned(up, 16);
        bI[s] = *(const half8*)__builtin_assume_aligned(up + 1024, 16);
      }
#pragma unroll
      for (int n = 0; n < 2; ++n) {
        const uint32_t cb = colAB + (uint32_t)(n << 12);
        f32x16 cX = {}, cY = {};
#pragma unroll
        for (int s = 0; s < 2; ++s) {
          const uint4 q0 = ld16(sb + cb + (uint32_t)((((s << 2) + (hi << 1) + 0) ^ swz) << 4));
          const uint4 q1 = ld16(sb + cb + (uint32_t)((((s << 2) + (hi << 1) + 1) ^ swz) << 4));
          const uint32_t dw[8] = {q0.x, q0.y, q0.z, q0.w, q1.x, q1.y, q1.z, q1.w};
          uint32_t ax[4], ay[4], an[4];
#pragma unroll
          for (int j = 0; j < 4; ++j) {
            ax[j] = __builtin_amdgcn_perm(dw[2 * j + 1], dw[2 * j], 0x05040100u);   // x halves
            ay[j] = __builtin_amdgcn_perm(dw[2 * j + 1], dw[2 * j], 0x07060302u);   // y halves
            an[j] = ay[j] ^ 0x80008000u;                                            // -y
          }
          const half8 aX = h8(ax[0], ax[1], ax[2], ax[3]);
          const half8 aY = h8(ay[0], ay[1], ay[2], ay[3]);
          const half8 aN = h8(an[0], an[1], an[2], an[3]);
          cX = __builtin_amdgcn_mfma_f32_32x32x16_f16(aX, bR[s], cX, 0, 0, 0);  // x' = Rx - Iy
          cX = __builtin_amdgcn_mfma_f32_32x32x16_f16(aN, bI[s], cX, 0, 0, 0);
          cY = __builtin_amdgcn_mfma_f32_32x32x16_f16(aX, bI[s], cY, 0, 0, 0);  // y' = Ix + Ry
          cY = __builtin_amdgcn_mfma_f32_32x32x16_f16(aY, bR[s], cY, 0, 0, 0);
        }
        // write L_B: lane's own col' (=l31); k' = c_M = (e&3)+8*(e>>2)+4hi, granule 2u+hi
#pragma unroll
        for (int u = 0; u < 4; ++u) {
          uint4 o;
          o.x = pkh2(cX[4 * u + 0], cY[4 * u + 0]); o.y = pkh2(cX[4 * u + 1], cY[4 * u + 1]);
          o.z = pkh2(cX[4 * u + 2], cY[4 * u + 2]); o.w = pkh2(cX[4 * u + 3], cY[4 * u + 3]);
          st16(sb + cb + (uint32_t)((((u << 1) + hi) ^ swz) << 4), o);
        }
      }
      __builtin_amdgcn_wave_barrier();
    }

    // ============ GB: qubits 8..4 (amp bits 5..9); preread-all -> barrier -> scatter to L_C ============
    {
      half8 bR[2], bI[2];
#pragma unroll
      for (int s = 0; s < 2; ++s) {
        const __half* up = Ul + 2048 + l31 * 32 + s * 16 + hi * 8;
        bR[s] = *(const half8*)__builtin_assume_aligned(up, 16);
        bI[s] = *(const half8*)__builtin_assume_aligned(up + 1024, 16);
      }
      uint4 dr[2][2][2];
#pragma unroll
      for (int n = 0; n < 2; ++n)
#pragma unroll
        for (int s = 0; s < 2; ++s)
#pragma unroll
          for (int j = 0; j < 2; ++j)
            dr[n][s][j] = ld16(sb + colAB + (uint32_t)(n << 12)
                               + (uint32_t)((((s << 2) + (hi << 1) + j) ^ swz) << 4));
      __syncthreads();   // all waves' L_B reads done before any L_C write lands anywhere
#pragma unroll
      for (int n = 0; n < 2; ++n) {
        f32x16 cX = {}, cY = {};
#pragma unroll
        for (int s = 0; s < 2; ++s) {
          const uint32_t dw[8] = {dr[n][s][0].x, dr[n][s][0].y, dr[n][s][0].z, dr[n][s][0].w,
                                  dr[n][s][1].x, dr[n][s][1].y, dr[n][s][1].z, dr[n][s][1].w};
          uint32_t ax[4], ay[4], an[4];
#pragma unroll
          for (int j = 0; j < 4; ++j) {
            ax[j] = __builtin_amdgcn_perm(dw[2 * j + 1], dw[2 * j], 0x05040100u);
            ay[j] = __builtin_amdgcn_perm(dw[2 * j + 1], dw[2 * j], 0x07060302u);
            an[j] = ay[j] ^ 0x80008000u;
          }
          const half8 aX = h8(ax[0], ax[1], ax[2], ax[3]);
          const half8 aY = h8(ay[0], ay[1], ay[2], ay[3]);
          const half8 aN = h8(an[0], an[1], an[2], an[3]);
          cX = __builtin_amdgcn_mfma_f32_32x32x16_f16(aX, bR[s], cX, 0, 0, 0);
          cX = __builtin_amdgcn_mfma_f32_32x32x16_f16(aN, bI[s], cX, 0, 0, 0);
          cY = __builtin_amdgcn_mfma_f32_32x32x16_f16(aX, bI[s], cY, 0, 0, 0);
          cY = __builtin_amdgcn_mfma_f32_32x32x16_f16(aY, bR[s], cY, 0, 0, 0);
        }
        const uint32_t lb = lbc ^ (uint32_t)(n << 2);        // k'' = n | (w<<1); n enters inner field
#pragma unroll
        for (int e = 0; e < 16; ++e)
          *(uint32_t*)(sb + (lb ^ ECT.v[e])) = pkh2(cX[e], cY[e]);
      }
      __syncthreads();   // L_C complete before GC reads
    }

    // ============ GC: qubits 3..0 (amp bits 10..13); + CNOT scatter (layers 0,1) or measure ============
    {
      const __half* up = Ul + 4096 + l15 * 16 + h4 * 4;      // blob [r=l15][k=4*h4]
      const half4 bR = *(const half4*)__builtin_assume_aligned(up, 8);
      const half4 bI = *(const half4*)__builtin_assume_aligned(up + 256, 8);
      uint4 dc[8];
#pragma unroll
      for (int i = 0; i < 8; ++i)
        dc[i] = ld16(sb + gcr + (uint32_t)(i << 10));
      __syncthreads();   // all waves' L_C reads done before scatter overwrites buffer
      float sE0[8], sE1[8], sE2[8];
#pragma unroll
      for (int i = 0; i < 8; ++i) {
        const int m2 = (i >> 1) & 3;                         // L_C inner swizzle (compile-time per i)
        const uint32_t ph[4] = {dc[i].x, dc[i].y, dc[i].z, dc[i].w};
        const uint32_t d0 = ph[0 ^ m2], d1 = ph[1 ^ m2], d2 = ph[2 ^ m2], d3 = ph[3 ^ m2];
        const uint32_t x0 = __builtin_amdgcn_perm(d1, d0, 0x05040100u);
        const uint32_t x1 = __builtin_amdgcn_perm(d3, d2, 0x05040100u);
        const uint32_t y0 = __builtin_amdgcn_perm(d1, d0, 0x07060302u);
        const uint32_t y1 = __builtin_amdgcn_perm(d3, d2, 0x07060302u);
        const half4 aX = h4v(x0, x1);
        const half4 aY = h4v(y0, y1);
        const half4 aN = h4v(y0 ^ 0x80008000u, y1 ^ 0x80008000u);
        f32x4 cX = {}, cY = {};
        cX = __builtin_amdgcn_mfma_f32_16x16x16f16(aX, bR, cX, 0, 0, 0);
        cX = __builtin_amdgcn_mfma_f32_16x16x16f16(aN, bI, cX, 0, 0, 0);
        cY = __builtin_amdgcn_mfma_f32_16x16x16f16(aX, bI, cY, 0, 0, 0);
        cY = __builtin_amdgcn_mfma_f32_16x16x16f16(aY, bR, cY, 0, 0, 0);
        if (li < 2) {
          // CNOT ring folded: element a -> write (x,y) at laddr(M(a)) = scb ^ SCT[i][reg]
#pragma unroll
          for (int r = 0; r < 4; ++r)
            *(uint32_t*)(sb + (scb ^ SCT.v[i][r])) = pkh2(cX[r], cY[r]);
        } else {
          // probabilities in f32 (pre-rounding) + partial sums over element bits {a0,a1}
          const float p0 = fmaf(cX[0], cX[0], cY[0] * cY[0]);
          const float p1 = fmaf(cX[1], cX[1], cY[1] * cY[1]);
          const float p2 = fmaf(cX[2], cX[2], cY[2] * cY[2]);
          const float p3 = fmaf(cX[3], cX[3], cY[3] * cY[3]);
          const float t01 = p0 + p1, t23 = p2 + p3;
          const float d01 = p0 - p1, d23 = p2 - p3;
          sE0[i] = t01 + t23;    // no sign
          sE1[i] = t01 - t23;    // (-1)^a1
          sE2[i] = d01 - d23;    // (-1)^(a0+a1)
        }
      }
      if (li < 2) {
        __syncthreads();         // next layer's GA reads the fresh L_A
      } else {
        // ---- measurement: out[q] = Walsh coefficient of |amp|^2 at row-mask of M (final CNOT folded)
        // element bits done above; now i-bits (a4..a6):
        float A = 0.f, Bv = 0.f, Cv = 0.f;
#pragma unroll
        for (int i = 0; i < 8; ++i) {
          if (__popc(i) & 1) { A -= sE2[i]; Bv -= sE1[i]; Cv -= sE0[i]; }
          else               { A += sE2[i]; Bv += sE1[i]; Cv += sE0[i]; }
        }
        const float u0 = sE0[0] + sE0[1], u1 = sE0[2] + sE0[3];
        const float u2 = sE0[4] + sE0[5], u3 = sE0[6] + sE0[7];
        float Dv = (u0 - u1) - (u2 - u3);   // (-1)^(a5+a6)
        float Ev = (u0 + u1) - (u2 + u3);   // (-1)^a6
        float Fv = (u0 + u1) + (u2 + u3);   // +
        // signed Walsh butterfly over lane bits (l0..l3 = a10..13, l4 = a2, l5 = a3)
#pragma unroll
        for (int m = 0; m < 6; ++m) {
          const int hb = 1 << m;
          const bool up2 = (l & hb) != 0;
          float u;
          u = __shfl_xor(A, hb, 64);  A  = up2 ? (u - A)  : (u + A);
          u = __shfl_xor(Bv, hb, 64); Bv = up2 ? (u - Bv) : (u + Bv);
          u = __shfl_xor(Cv, hb, 64); Cv = up2 ? (u - Cv) : (u + Cv);
          u = __shfl_xor(Dv, hb, 64); Dv = up2 ? (u - Dv) : (u + Dv);
          u = __shfl_xor(Ev, hb, 64); Ev = up2 ? (u - Ev) : (u + Ev);
          u = __shfl_xor(Fv, hb, 64); Fv = up2 ? (u - Fv) : (u + Fv);
        }
        const float swv = (__popc(w) & 1) ? -1.f : 1.f;   // wave bits = a7..a9
        if (l == 63)      { red[w][13] = swv * A; red[w][12] = swv * Bv; red[w][11] = swv * Cv; }
        else if (l == 55) { red[w][0]  = swv * A; }
        else if (l == 47) { red[w][10] = swv * Cv; }
        else if (l == 15) { red[w][9] = swv * Cv; red[w][8] = swv * Dv; red[w][7] = swv * Ev;
                            red[w][6] = swv * Fv;
                            red[w][5] = (__popc(w >> 1) & 1) ? -Fv : Fv;
                            red[w][4] = ((w >> 2) & 1) ? -Fv : Fv;
                            red[w][3] = Fv; }
        else if (l == 14) { red[w][2] = Fv; }
        else if (l == 12) { red[w][1] = Fv; }
      }
    }
  }

  __syncthreads();
  if (t < NQ) {
    float sq = 0.f;
#pragma unroll
    for (int ww = 0; ww < 8; ++ww) sq += red[ww][t];
    out[b * NQ + t] = sq;
  }
}

extern "C" void kernel_launch(void* const* d_in, const int* in_sizes, int n_in,
                              void* d_out, int out_size, void* d_ws, size_t ws_size,
                              hipStream_t stream) {
  const float* x      = (const float*)d_in[0];
  const float* params = (const float*)d_in[1];
  float* out          = (float*)d_out;
  __half* U           = (__half*)d_ws;       // needs 3*4608*2 = 27648 B of workspace
  uprep_kernel<<<27, 256, 0, stream>>>(params, U);
  qsim_kernel<<<BATCH, 512, 0, stream>>>(x, params, (const __half*)U, out);
}

// Round 3
// 152.292 us; speedup vs baseline: 1.0722x; 1.0348x over previous
//
#include <hip/hip_runtime.h>
#include <hip/hip_fp16.h>
#include <stdint.h>

#define NQ     14
#define NL     4
#define BATCH  2048
#define DIM    16384

using half8  = __attribute__((ext_vector_type(8)))  _Float16;
using half4  = __attribute__((ext_vector_type(4)))  _Float16;
using f32x16 = __attribute__((ext_vector_type(16))) float;
using f32x4  = __attribute__((ext_vector_type(4)))  float;

// ================= compile-time maps =================
// CNOT ring: image mask of input bit b: M(e_b) = bits0..b|bit13 (b<=12); M(e_13)=bits0..12
constexpr uint32_t mmask(int b) { return b < 13 ? (((1u << (b + 1)) - 1u) | 0x2000u) : 0x1FFFu; }
// L_A byte address of amp a (4 B/amp: packed (x,y) f16):
//   col = a>>5 (128 B/col), 16B-granule = (a>>2)&7 XOR col&7, inner = a&3.  GF(2)-linear.
constexpr uint32_t laddr(uint32_t a) {
  return ((a >> 5) << 7) ^ (((((a >> 2) & 7u) ^ ((a >> 5) & 7u)) & 7u) << 4) ^ ((a & 3u) << 2);
}
constexpr uint32_t IMG(int b) { return laddr(mmask(b)); }  // addr-image of amp-bit b after CNOT

struct TabEmb { uint32_t v[32]; constexpr TabEmb() : v() {
  for (int k = 0; k < 32; ++k) { uint32_t x = 0;
    for (int b = 0; b < 5; ++b) if ((k >> b) & 1) x ^= IMG(b); v[k] = x; } } };
constexpr TabEmb EMBT{};

// GC scatter element constants: element bits (i -> a4..a6, reg -> a0..a1)
struct TabSc { uint32_t v[8][4]; constexpr TabSc() : v() {
  for (int i = 0; i < 8; ++i) for (int r = 0; r < 4; ++r) { uint32_t x = 0;
    if (r & 1) x ^= IMG(0); if (r & 2) x ^= IMG(1);
    if (i & 1) x ^= IMG(4); if (i & 2) x ^= IMG(5); if (i & 4) x ^= IMG(6);
    v[i][r] = x; } } };
constexpr TabSc SCT{};

// GB -> L_C element constants. L_C: 64 B/col'', addr = col''*64
//   ^ (((k''>>2) ^ sg(col''))<<4) ^ (((k''&3) ^ sin(col''))<<2)
// element part: ce = (e&3)|((e>>2)<<3).  Linear in e: e0->0x50, e1->0xA0, e2->0x220, e3->0x400.
struct TabEc { uint32_t v[16]; constexpr TabEc() : v() {
  for (int e = 0; e < 16; ++e) { uint32_t ce = (uint32_t)((e & 3) | ((e >> 2) << 3));
    v[e] = (ce << 6) ^ (((ce ^ (ce >> 2)) & 3u) << 4); } } };
constexpr TabEc ECT{};

__device__ __forceinline__ half8 h8(uint32_t a, uint32_t b, uint32_t c, uint32_t d) {
  union { uint32_t u[4]; half8 h; } z; z.u[0]=a; z.u[1]=b; z.u[2]=c; z.u[3]=d; return z.h; }
__device__ __forceinline__ half4 h4v(uint32_t a, uint32_t b) {
  union { uint32_t u[2]; half4 h; } z; z.u[0]=a; z.u[1]=b; return z.h; }
__device__ __forceinline__ uint4 ld16(const char* p) {
  return *(const uint4*)__builtin_assume_aligned(p, 16); }
__device__ __forceinline__ void st16(char* p, uint4 v) {
  *(uint4*)__builtin_assume_aligned(p, 16) = v; }
__device__ __forceinline__ uint32_t pkh2(float a, float b) {
  return __builtin_bit_cast(uint32_t, __floats2half2_rn(a, b)); }

// ================= prep kernel: U matrices per layer/group =================
__global__ void uprep_kernel(const float* __restrict__ params, __half* __restrict__ U) {
  const int id = blockIdx.x * 256 + threadIdx.x;   // 27*256 = 6912 cells exactly
  int li, grp, r, k, nb, off, mstride;
  if (id < 6144) { li = id >> 11; const int sub = id & 2047;
    grp = sub >> 10; const int cell = sub & 1023; r = cell >> 5; k = cell & 31; nb = 5;
    off = li * 4608 + grp * 2048 + r * 32 + k; mstride = 1024; }
  else { const int id2 = id - 6144; li = id2 >> 8; const int cell = id2 & 255;
    grp = 2; r = cell >> 4; k = cell & 15; nb = 4;
    off = li * 4608 + 4096 + r * 16 + k; mstride = 256; }
  const float* th = params + (li + 1) * NQ;
  float mag = 1.f; int d = 0;
  for (int j = 0; j < nb; ++j) {
    const int pbit = (grp == 0) ? j : (grp == 1) ? 5 + j : 10 + j;
    const float ph = 0.5f * th[13 - pbit];
    const int df = ((r >> j) ^ (k >> j)) & 1;
    mag *= df ? sinf(ph) : cosf(ph);
    d += df;
  }
  float R = 0.f, I = 0.f;
  switch (d & 3) { case 0: R = mag; break; case 1: I = -mag; break;
                   case 2: R = -mag; break; default: I = mag; break; }
  U[off] = __float2half_rn(R);
  U[off + mstride] = __float2half_rn(I);
}

// ================= main kernel =================
// Identical layouts/sync to the verified 120us kernel. Only change: the three scalar
// scatters (embed, GB->L_C, GC->L_A) are ORDER-STAGGERED per lane: at step s we write
// element s^sigma(lane). Since all maps are XOR-linear, addr = (base ^ T[sigma]) ^ T[s]
// with static table indices; values are permuted by a 2-stage cndmask butterfly.
// The (address,value) write-set is bit-identical to the verified kernel.
__global__ __launch_bounds__(512)
__attribute__((amdgpu_waves_per_eu(4, 4)))
void qsim_kernel(const float* __restrict__ x, const float* __restrict__ params,
                 const __half* __restrict__ U, float* __restrict__ out) {
  __shared__ uint32_t lds[DIM];          // 64 KB state
  __shared__ float red[8][16];
  __shared__ float exc[NQ], exs[NQ];
  char* const sb = (char*)lds;

  const int b = blockIdx.x;
  const int t = threadIdx.x;
  const int w = t >> 6, l = t & 63;
  const int hi = l >> 5, l31 = l & 31, l15 = l & 15, h4 = (l >> 4) & 3;
  const int swz = l & 7;

  if (t < NQ) { const float xv = x[b * NQ + t] + params[t];
                exc[t] = cosf(0.5f * xv); exs[t] = sinf(0.5f * xv); }
  __syncthreads();

  const uint32_t colAB = (uint32_t)(((w << 6) | l31) << 7);
  const uint32_t sgl = (uint32_t)(((l15 ^ (l15 >> 2)) ^ w) & 3);
  const uint32_t gcr = (uint32_t)((w << 13) | (l15 << 6) | (((h4 ^ (int)sgl) & 3) << 4));
  const uint32_t lbc = ((uint32_t)l31 << 11) ^ ((uint32_t)hi << 8)
      ^ ((uint32_t)(((w >> 1) ^ ((l31 >> 2) & 3) ^ hi) & 3) << 4)
      ^ ((uint32_t)(((w << 1) ^ l) & 3) << 2);
  uint32_t scb = 0;
  { if (l & 16) scb ^= IMG(2);
    if (l & 32) scb ^= IMG(3);
#pragma unroll
    for (int j = 0; j < 4; ++j) if ((l15 >> j) & 1) scb ^= IMG(10 + j);
#pragma unroll
    for (int j = 0; j < 3; ++j) if ((w >> j) & 1) scb ^= IMG(7 + j); }

  // stagger bases (fold T[sigma] into the write base; pure reorder, same write-set)
  const bool gcs0 = (l & 1), gcs1 = (l & 2);                 // GC sigma_r = l&3
  const uint32_t scb2 = scb ^ (gcs0 ? IMG(0) : 0u) ^ (gcs1 ? IMG(1) : 0u);
  const bool gbs0 = (l & 16), gbs1 = (l & 4);                // GB sigma_e = (l4, l2)
  const uint32_t lbc2 = lbc ^ (gbs0 ? 0x50u : 0u) ^ (gbs1 ? 0xA0u : 0u);

  // ---- embedding: thread t owns amps a = 32t + k; staggered write order (sigma = t&31) ----
  {
    float pb = 1.f;
#pragma unroll
    for (int j = 0; j < 9; ++j) pb *= ((t >> j) & 1) ? exs[8 - j] : exc[8 - j];
    uint32_t eb = 0;
#pragma unroll
    for (int j = 0; j < 9; ++j) if ((t >> j) & 1) eb ^= IMG(5 + j);
    const int sgk = t & 31;
    if (sgk & 1)  eb ^= IMG(0);
    if (sgk & 2)  eb ^= IMG(1);
    if (sgk & 4)  eb ^= IMG(2);
    if (sgk & 8)  eb ^= IMG(3);
    if (sgk & 16) eb ^= IMG(4);
    const int pct = __popc(t);
#pragma unroll
    for (int k = 0; k < 32; ++k) {
      const int idx = k ^ sgk;                 // element actually written this step
      float f = pb;
      f *= (idx & 1)  ? exs[13] : exc[13];
      f *= (idx & 2)  ? exs[12] : exc[12];
      f *= (idx & 4)  ? exs[11] : exc[11];
      f *= (idx & 8)  ? exs[10] : exc[10];
      f *= (idx & 16) ? exs[9]  : exc[9];
      const int pc = (pct + __popc(idx)) & 3;
      const float xr = (pc == 0) ? f : ((pc == 2) ? -f : 0.f);
      const float yi = (pc == 1) ? -f : ((pc == 3) ? f : 0.f);
      *(uint32_t*)(sb + (eb ^ EMBT.v[k])) = pkh2(xr, yi);
    }
  }
  __syncthreads();

#pragma unroll 1
  for (int li = 0; li < 3; ++li) {
    const __half* Ul = U + li * 4608;

    // ============ GA: qubits 13..9 (amp bits 0..4); lane-private in-place ============
    {
      half8 bR[2], bI[2];
#pragma unroll
      for (int s = 0; s < 2; ++s) {
        const __half* up = Ul + l31 * 32 + s * 16 + hi * 8;
        bR[s] = *(const half8*)__builtin_assume_aligned(up, 16);
        bI[s] = *(const half8*)__builtin_assume_aligned(up + 1024, 16);
      }
#pragma unroll
      for (int n = 0; n < 2; ++n) {
        const uint32_t cb = colAB + (uint32_t)(n << 12);
        f32x16 cX = {}, cY = {};
#pragma unroll
        for (int s = 0; s < 2; ++s) {
          const uint4 q0 = ld16(sb + cb + (uint32_t)((((s << 2) + (hi << 1) + 0) ^ swz) << 4));
          const uint4 q1 = ld16(sb + cb + (uint32_t)((((s << 2) + (hi << 1) + 1) ^ swz) << 4));
          const uint32_t dw[8] = {q0.x, q0.y, q0.z, q0.w, q1.x, q1.y, q1.z, q1.w};
          uint32_t ax[4], ay[4], an[4];
#pragma unroll
          for (int j = 0; j < 4; ++j) {
            ax[j] = __builtin_amdgcn_perm(dw[2 * j + 1], dw[2 * j], 0x05040100u);
            ay[j] = __builtin_amdgcn_perm(dw[2 * j + 1], dw[2 * j], 0x07060302u);
            an[j] = ay[j] ^ 0x80008000u;
          }
          const half8 aX = h8(ax[0], ax[1], ax[2], ax[3]);
          const half8 aY = h8(ay[0], ay[1], ay[2], ay[3]);
          const half8 aN = h8(an[0], an[1], an[2], an[3]);
          cX = __builtin_amdgcn_mfma_f32_32x32x16_f16(aX, bR[s], cX, 0, 0, 0);
          cX = __builtin_amdgcn_mfma_f32_32x32x16_f16(aN, bI[s], cX, 0, 0, 0);
          cY = __builtin_amdgcn_mfma_f32_32x32x16_f16(aX, bI[s], cY, 0, 0, 0);
          cY = __builtin_amdgcn_mfma_f32_32x32x16_f16(aY, bR[s], cY, 0, 0, 0);
        }
#pragma unroll
        for (int u = 0; u < 4; ++u) {
          uint4 o;
          o.x = pkh2(cX[4 * u + 0], cY[4 * u + 0]); o.y = pkh2(cX[4 * u + 1], cY[4 * u + 1]);
          o.z = pkh2(cX[4 * u + 2], cY[4 * u + 2]); o.w = pkh2(cX[4 * u + 3], cY[4 * u + 3]);
          st16(sb + cb + (uint32_t)((((u << 1) + hi) ^ swz) << 4), o);
        }
      }
      __builtin_amdgcn_wave_barrier();
    }

    // ============ GB: qubits 8..4 (amp bits 5..9); staggered scatter to L_C ============
    {
      half8 bR[2], bI[2];
#pragma unroll
      for (int s = 0; s < 2; ++s) {
        const __half* up = Ul + 2048 + l31 * 32 + s * 16 + hi * 8;
        bR[s] = *(const half8*)__builtin_assume_aligned(up, 16);
        bI[s] = *(const half8*)__builtin_assume_aligned(up + 1024, 16);
      }
      uint4 dr[2][2][2];
#pragma unroll
      for (int n = 0; n < 2; ++n)
#pragma unroll
        for (int s = 0; s < 2; ++s)
#pragma unroll
          for (int j = 0; j < 2; ++j)
            dr[n][s][j] = ld16(sb + colAB + (uint32_t)(n << 12)
                               + (uint32_t)((((s << 2) + (hi << 1) + j) ^ swz) << 4));
      __syncthreads();   // all L_B reads done before any L_C write
#pragma unroll
      for (int n = 0; n < 2; ++n) {
        f32x16 cX = {}, cY = {};
#pragma unroll
        for (int s = 0; s < 2; ++s) {
          const uint32_t dw[8] = {dr[n][s][0].x, dr[n][s][0].y, dr[n][s][0].z, dr[n][s][0].w,
                                  dr[n][s][1].x, dr[n][s][1].y, dr[n][s][1].z, dr[n][s][1].w};
          uint32_t ax[4], ay[4], an[4];
#pragma unroll
          for (int j = 0; j < 4; ++j) {
            ax[j] = __builtin_amdgcn_perm(dw[2 * j + 1], dw[2 * j], 0x05040100u);
            ay[j] = __builtin_amdgcn_perm(dw[2 * j + 1], dw[2 * j], 0x07060302u);
            an[j] = ay[j] ^ 0x80008000u;
          }
          const half8 aX = h8(ax[0], ax[1], ax[2], ax[3]);
          const half8 aY = h8(ay[0], ay[1], ay[2], ay[3]);
          const half8 aN = h8(an[0], an[1], an[2], an[3]);
          cX = __builtin_amdgcn_mfma_f32_32x32x16_f16(aX, bR[s], cX, 0, 0, 0);
          cX = __builtin_amdgcn_mfma_f32_32x32x16_f16(aN, bI[s], cX, 0, 0, 0);
          cY = __builtin_amdgcn_mfma_f32_32x32x16_f16(aX, bI[s], cY, 0, 0, 0);
          cY = __builtin_amdgcn_mfma_f32_32x32x16_f16(aY, bR[s], cY, 0, 0, 0);
        }
        const uint32_t lb = lbc2 ^ (uint32_t)(n << 2);
        uint32_t pk[16];
#pragma unroll
        for (int e = 0; e < 16; ++e) pk[e] = pkh2(cX[e], cY[e]);
#pragma unroll
        for (int q = 0; q < 4; ++q) {
          const uint32_t a0 = pk[4 * q + 0], a1 = pk[4 * q + 1];
          const uint32_t a2 = pk[4 * q + 2], a3 = pk[4 * q + 3];
          const uint32_t b0 = gbs0 ? a1 : a0, b1 = gbs0 ? a0 : a1;
          const uint32_t b2 = gbs0 ? a3 : a2, b3 = gbs0 ? a2 : a3;
          const uint32_t c0 = gbs1 ? b2 : b0, c1 = gbs1 ? b3 : b1;
          const uint32_t c2 = gbs1 ? b0 : b2, c3 = gbs1 ? b1 : b3;
          *(uint32_t*)(sb + (lb ^ ECT.v[4 * q + 0])) = c0;
          *(uint32_t*)(sb + (lb ^ ECT.v[4 * q + 1])) = c1;
          *(uint32_t*)(sb + (lb ^ ECT.v[4 * q + 2])) = c2;
          *(uint32_t*)(sb + (lb ^ ECT.v[4 * q + 3])) = c3;
        }
      }
      __syncthreads();   // L_C complete before GC reads
    }

    // ============ GC: qubits 3..0 (amp bits 10..13); staggered scatter / measure ============
    {
      const __half* up = Ul + 4096 + l15 * 16 + h4 * 4;
      const half4 bR = *(const half4*)__builtin_assume_aligned(up, 8);
      const half4 bI = *(const half4*)__builtin_assume_aligned(up + 256, 8);
      uint4 dc[8];
#pragma unroll
      for (int i = 0; i < 8; ++i)
        dc[i] = ld16(sb + gcr + (uint32_t)(i << 10));
      __syncthreads();   // all L_C reads done before scatter overwrites buffer
      float sE0[8], sE1[8], sE2[8];
#pragma unroll
      for (int i = 0; i < 8; ++i) {
        const int m2 = (i >> 1) & 3;
        const uint32_t ph[4] = {dc[i].x, dc[i].y, dc[i].z, dc[i].w};
        const uint32_t d0 = ph[0 ^ m2], d1 = ph[1 ^ m2], d2 = ph[2 ^ m2], d3 = ph[3 ^ m2];
        const uint32_t x0 = __builtin_amdgcn_perm(d1, d0, 0x05040100u);
        const uint32_t x1 = __builtin_amdgcn_perm(d3, d2, 0x05040100u);
        const uint32_t y0 = __builtin_amdgcn_perm(d1, d0, 0x07060302u);
        const uint32_t y1 = __builtin_amdgcn_perm(d3, d2, 0x07060302u);
        const half4 aX = h4v(x0, x1);
        const half4 aY = h4v(y0, y1);
        const half4 aN = h4v(y0 ^ 0x80008000u, y1 ^ 0x80008000u);
        f32x4 cX = {}, cY = {};
        cX = __builtin_amdgcn_mfma_f32_16x16x16f16(aX, bR, cX, 0, 0, 0);
        cX = __builtin_amdgcn_mfma_f32_16x16x16f16(aN, bI, cX, 0, 0, 0);
        cY = __builtin_amdgcn_mfma_f32_16x16x16f16(aX, bI, cY, 0, 0, 0);
        cY = __builtin_amdgcn_mfma_f32_16x16x16f16(aY, bR, cY, 0, 0, 0);
        if (li < 2) {
          // staggered CNOT-fold scatter: step sr writes element r = sr ^ (l&3)
          const uint32_t p0 = pkh2(cX[0], cY[0]), p1 = pkh2(cX[1], cY[1]);
          const uint32_t p2 = pkh2(cX[2], cY[2]), p3 = pkh2(cX[3], cY[3]);
          const uint32_t q0 = gcs0 ? p1 : p0, q1 = gcs0 ? p0 : p1;
          const uint32_t q2 = gcs0 ? p3 : p2, q3 = gcs0 ? p2 : p3;
          const uint32_t r0 = gcs1 ? q2 : q0, r1 = gcs1 ? q3 : q1;
          const uint32_t r2 = gcs1 ? q0 : q2, r3 = gcs1 ? q1 : q3;
          *(uint32_t*)(sb + (scb2 ^ SCT.v[i][0])) = r0;
          *(uint32_t*)(sb + (scb2 ^ SCT.v[i][1])) = r1;
          *(uint32_t*)(sb + (scb2 ^ SCT.v[i][2])) = r2;
          *(uint32_t*)(sb + (scb2 ^ SCT.v[i][3])) = r3;
        } else {
          const float p0 = fmaf(cX[0], cX[0], cY[0] * cY[0]);
          const float p1 = fmaf(cX[1], cX[1], cY[1] * cY[1]);
          const float p2 = fmaf(cX[2], cX[2], cY[2] * cY[2]);
          const float p3 = fmaf(cX[3], cX[3], cY[3] * cY[3]);
          const float t01 = p0 + p1, t23 = p2 + p3;
          const float d01 = p0 - p1, d23 = p2 - p3;
          sE0[i] = t01 + t23;
          sE1[i] = t01 - t23;
          sE2[i] = d01 - d23;
        }
      }
      if (li < 2) {
        __syncthreads();         // next layer's GA reads fresh L_A
      } else {
        float A = 0.f, Bv = 0.f, Cv = 0.f;
#pragma unroll
        for (int i = 0; i < 8; ++i) {
          if (__popc(i) & 1) { A -= sE2[i]; Bv -= sE1[i]; Cv -= sE0[i]; }
          else               { A += sE2[i]; Bv += sE1[i]; Cv += sE0[i]; }
        }
        const float u0 = sE0[0] + sE0[1], u1 = sE0[2] + sE0[3];
        const float u2 = sE0[4] + sE0[5], u3 = sE0[6] + sE0[7];
        float Dv = (u0 - u1) - (u2 - u3);
        float Ev = (u0 + u1) - (u2 + u3);
        float Fv = (u0 + u1) + (u2 + u3);
#pragma unroll
        for (int m = 0; m < 6; ++m) {
          const int hb = 1 << m;
          const bool up2 = (l & hb) != 0;
          float u;
          u = __shfl_xor(A, hb, 64);  A  = up2 ? (u - A)  : (u + A);
          u = __shfl_xor(Bv, hb, 64); Bv = up2 ? (u - Bv) : (u + Bv);
          u = __shfl_xor(Cv, hb, 64); Cv = up2 ? (u - Cv) : (u + Cv);
          u = __shfl_xor(Dv, hb, 64); Dv = up2 ? (u - Dv) : (u + Dv);
          u = __shfl_xor(Ev, hb, 64); Ev = up2 ? (u - Ev) : (u + Ev);
          u = __shfl_xor(Fv, hb, 64); Fv = up2 ? (u - Fv) : (u + Fv);
        }
        const float swv = (__popc(w) & 1) ? -1.f : 1.f;
        if (l == 63)      { red[w][13] = swv * A; red[w][12] = swv * Bv; red[w][11] = swv * Cv; }
        else if (l == 55) { red[w][0]  = swv * A; }
        else if (l == 47) { red[w][10] = swv * Cv; }
        else if (l == 15) { red[w][9] = swv * Cv; red[w][8] = swv * Dv; red[w][7] = swv * Ev;
                            red[w][6] = swv * Fv;
                            red[w][5] = (__popc(w >> 1) & 1) ? -Fv : Fv;
                            red[w][4] = ((w >> 2) & 1) ? -Fv : Fv;
                            red[w][3] = Fv; }
        else if (l == 14) { red[w][2] = Fv; }
        else if (l == 12) { red[w][1] = Fv; }
      }
    }
  }

  __syncthreads();
  if (t < NQ) {
    float sq = 0.f;
#pragma unroll
    for (int ww = 0; ww < 8; ++ww) sq += red[ww][t];
    out[b * NQ + t] = sq;
  }
}

extern "C" void kernel_launch(void* const* d_in, const int* in_sizes, int n_in,
                              void* d_out, int out_size, void* d_ws, size_t ws_size,
                              hipStream_t stream) {
  const float* x      = (const float*)d_in[0];
  const float* params = (const float*)d_in[1];
  float* out          = (float*)d_out;
  __half* U           = (__half*)d_ws;       // 3*4608*2 = 27648 B of workspace
  uprep_kernel<<<27, 256, 0, stream>>>(params, U);
  qsim_kernel<<<BATCH, 512, 0, stream>>>(x, params, (const __half*)U, out);
}